// Round 9
// baseline (258.502 us; speedup 1.0000x reference)
//
#include <hip/hip_runtime.h>

// GCNConv: out = D^-1/2 (A+I) D^-1/2 X W + b
// N=100000, E=1600000, Din=Dout=128; x/W/b fp32, edge_index int32, out fp32.
//
// R13 = R12 (248.5us) + gemm spread across ALL underfilled dispatches.
//   k_wprep (3us micro-kernel) -> Wtg ready before any gemm rider.
//   gemm blocks split 4 ways: ~390 ride scan1 (was a 150-block dispatch),
//   ~390 ride scan2 (was a 1-block dispatch!), ~390 ride place, rest ride
//   fine. Each chunk < 1280 blocks (one occupancy-wave at 5 blk/CU) so it
//   executes concurrently with its host kernel instead of queueing behind
//   place. place/fine/gather are R12's verified code paths, unchanged.

#define ELEMS_PER_SCAN_BLOCK 4096  // 256 threads * 16
#define SCAN_SHIFT 12
#define CHUNK 2048                 // edges per hist/place block
#define NCMAX 800                  // >= NC = ceil(N/128) = 782

typedef __attribute__((ext_vector_type(8))) short short8;
typedef __attribute__((ext_vector_type(4))) float f32x4;

__device__ inline unsigned short f2bf(float f) {  // fp32 -> bf16 RNE
    unsigned u = __float_as_uint(f);
    u += 0x7fffu + ((u >> 16) & 1u);
    return (unsigned short)(u >> 16);
}
__device__ inline float bf_lo(unsigned u) { return __uint_as_float(u << 16); }
__device__ inline float bf_hi(unsigned u) { return __uint_as_float(u & 0xffff0000u); }

// ---- W transpose + bf16 convert (micro-kernel, runs first) ----
__global__ void k_wprep(const float* __restrict__ W, unsigned short* __restrict__ Wtg) {
    int n = blockIdx.x;
    int k = threadIdx.x;
    Wtg[n * 128 + k] = f2bf(W[k * 128 + n]);
}

// ---- coarse histogram (pure) ----
__global__ __launch_bounds__(256) void k_hist(const int* __restrict__ col,
                                              int* __restrict__ histg,
                                              int E, int NC, int NBLK) {
    __shared__ int lh[1024];
    int t = threadIdx.x, blk = blockIdx.x;
    for (int i = t; i < 1024; i += 256) lh[i] = 0;
    __syncthreads();
    int base = blk * CHUNK;
    #pragma unroll
    for (int i = 0; i < CHUNK / 256; ++i) {
        int e = base + i * 256 + t;
        if (e < E) atomicAdd(&lh[col[e] >> 7], 1);
    }
    __syncthreads();
    for (int b = t; b < NC; b += 256) histg[b * NBLK + blk] = lh[b];
}

__device__ inline int wave_incl_scan(int x, int lane) {
    #pragma unroll
    for (int d = 1; d < 64; d <<= 1) {
        int y = __shfl_up(x, d, 64);
        if (lane >= d) x += y;
    }
    return x;
}

// ---- gemm smem (K-split halves): 27.6KB ----
struct GSmem { short Xs[64][72]; short Ws[128][72]; };  // 144B rows: 16B-aligned

__device__ __forceinline__ void gemm_body(GSmem& sm, const float* __restrict__ x,
                                          const unsigned short* __restrict__ Wtg,
                                          unsigned short* __restrict__ h,
                                          int row0, int N, int t) {
    int lane = t & 63, wid = t >> 6;
    int q = lane >> 4;
    int m = lane & 15;
    f32x4 acc[8];
    #pragma unroll
    for (int tde = 0; tde < 8; ++tde) acc[tde] = (f32x4){0.f, 0.f, 0.f, 0.f};

    #pragma unroll
    for (int kh = 0; kh < 2; ++kh) {
        {   // X half: 64 rows x 64 K; 16 floats/thread
            int r = t >> 2;
            int kf = (t & 3) * 16;
            int gr = row0 + r;
            const float4* src = (const float4*)(x + (size_t)gr * 128 + kh * 64 + kf);
            float4 a0 = make_float4(0.f, 0.f, 0.f, 0.f), a1 = a0, a2 = a0, a3 = a0;
            if (gr < N) { a0 = src[0]; a1 = src[1]; a2 = src[2]; a3 = src[3]; }
            short8 p0, p1;
            p0[0] = (short)f2bf(a0.x); p0[1] = (short)f2bf(a0.y);
            p0[2] = (short)f2bf(a0.z); p0[3] = (short)f2bf(a0.w);
            p0[4] = (short)f2bf(a1.x); p0[5] = (short)f2bf(a1.y);
            p0[6] = (short)f2bf(a1.z); p0[7] = (short)f2bf(a1.w);
            p1[0] = (short)f2bf(a2.x); p1[1] = (short)f2bf(a2.y);
            p1[2] = (short)f2bf(a2.z); p1[3] = (short)f2bf(a2.w);
            p1[4] = (short)f2bf(a3.x); p1[5] = (short)f2bf(a3.y);
            p1[6] = (short)f2bf(a3.z); p1[7] = (short)f2bf(a3.w);
            *(short8*)&sm.Xs[r][kf]     = p0;
            *(short8*)&sm.Xs[r][kf + 8] = p1;
        }
        {   // W half: 128 rows x 64 K; 32 shorts/thread
            int n = t >> 1;
            int off = (t & 1) * 32;
            const short* wsrc = (const short*)Wtg + n * 128 + kh * 64 + off;
            #pragma unroll
            for (int i = 0; i < 4; ++i)
                *(short8*)&sm.Ws[n][off + 8 * i] = *(const short8*)(wsrc + 8 * i);
        }
        __syncthreads();
        #pragma unroll
        for (int kc = 0; kc < 64; kc += 32) {
            short8 af = *(const short8*)&sm.Xs[wid * 16 + m][kc + q * 8];
            #pragma unroll
            for (int tde = 0; tde < 8; ++tde) {
                short8 bf = *(const short8*)&sm.Ws[tde * 16 + m][kc + q * 8];
                acc[tde] = __builtin_amdgcn_mfma_f32_16x16x32_bf16(af, bf, acc[tde], 0, 0, 0);
            }
        }
        __syncthreads();
    }
    #pragma unroll
    for (int r = 0; r < 4; ++r) {
        int grow = row0 + wid * 16 + q * 4 + r;
        if (grow < N) {
            #pragma unroll
            for (int tde = 0; tde < 8; ++tde)
                h[(size_t)grow * 128 + tde * 16 + m] = f2bf(acc[tde][r]);
        }
    }
}

// ---- scan1 + gemm riders ----
__global__ __launch_bounds__(256) void k_scan1(const int* __restrict__ in,
                                               int* __restrict__ out,
                                               int* __restrict__ bsum, int M,
                                               const float* __restrict__ x,
                                               const unsigned short* __restrict__ Wtg,
                                               unsigned short* __restrict__ h,
                                               int N, int NSC, int gbase) {
    __shared__ union { struct { int wsum[4]; int woff[4]; } s; GSmem g; } sm;
    int t = threadIdx.x;
    if ((int)blockIdx.x >= NSC) {  // gemm rider
        gemm_body(sm.g, x, Wtg, h, (gbase + (int)blockIdx.x - NSC) * 64, N, t);
        return;
    }
    int lane = t & 63, wid = t >> 6;
    int base = blockIdx.x * ELEMS_PER_SCAN_BLOCK + t * 16;
    int v[16];
    #pragma unroll
    for (int i = 0; i < 16; ++i) v[i] = (base + i < M) ? in[base + i] : 0;
    int run = 0;
    #pragma unroll
    for (int i = 0; i < 16; ++i) { int xk = v[i]; v[i] = run; run += xk; }
    int incl = wave_incl_scan(run, lane);
    int excl = incl - run;
    if (lane == 63) sm.s.wsum[wid] = incl;
    __syncthreads();
    if (t == 0) {
        int r = 0;
        #pragma unroll
        for (int w = 0; w < 4; ++w) { int s = sm.s.wsum[w]; sm.s.woff[w] = r; r += s; }
        bsum[blockIdx.x] = r;
    }
    __syncthreads();
    int off = sm.s.woff[wid] + excl;
    #pragma unroll
    for (int i = 0; i < 16; ++i)
        if (base + i < M) out[base + i] = v[i] + off;
}

// ---- scan2 + gemm riders ----
__global__ __launch_bounds__(256) void k_scan2(const int* __restrict__ bsum,
                                               int* __restrict__ boff, int NB,
                                               const float* __restrict__ x,
                                               const unsigned short* __restrict__ Wtg,
                                               unsigned short* __restrict__ h,
                                               int N, int gbase) {
    __shared__ union { struct { int wsum[4]; int woff[4]; } s; GSmem g; } sm;
    int t = threadIdx.x;
    if ((int)blockIdx.x >= 1) {  // gemm rider
        gemm_body(sm.g, x, Wtg, h, (gbase + (int)blockIdx.x - 1) * 64, N, t);
        return;
    }
    int lane = t & 63, wid = t >> 6;
    int xk = (t < NB) ? bsum[t] : 0;
    int incl = wave_incl_scan(xk, lane);
    int excl = incl - xk;
    if (lane == 63) sm.s.wsum[wid] = incl;
    __syncthreads();
    if (t == 0) {
        int r = 0;
        #pragma unroll
        for (int w = 0; w < 4; ++w) { int s = sm.s.wsum[w]; sm.s.woff[w] = r; r += s; }
    }
    __syncthreads();
    if (t < NB) boff[t] = sm.s.woff[wid] + excl;
}

// ---- fused: place (blocks [0,NBLK)) + gemm riders ----
__global__ __launch_bounds__(256) void k_pg(const int* __restrict__ row,
                                            const int* __restrict__ col,
                                            const float* __restrict__ wgt,
                                            const int* __restrict__ histg,
                                            const int* __restrict__ boff,
                                            int2* __restrict__ srw,
                                            const float* __restrict__ x,
                                            const unsigned short* __restrict__ Wtg,
                                            unsigned short* __restrict__ h,
                                            int E, int N, int NC, int NBLK, int gbase) {
    __shared__ union {
        struct { int lcnt[NCMAX]; int gadj[NCMAX]; int2 stage[CHUNK]; int sdst[CHUNK];
                 int wsum[4]; int woff[4]; } p;   // 30.0 KB
        GSmem g;                                  // 27.6 KB
    } sm;
    int t = threadIdx.x;
    if ((int)blockIdx.x >= NBLK) {  // gemm rider
        gemm_body(sm.g, x, Wtg, h, (gbase + (int)blockIdx.x - NBLK) * 64, N, t);
        return;
    }
    int blk = blockIdx.x;
    int lane = t & 63, wid = t >> 6;
    int base = blk * CHUNK;
    int nE = min(CHUNK, E - base);
    for (int b = t; b < NCMAX; b += 256) sm.p.lcnt[b] = 0;
    __syncthreads();
    // pass A: local count
    #pragma unroll
    for (int i = 0; i < CHUNK / 256; ++i) {
        int e = base + i * 256 + t;
        if (e < E) atomicAdd(&sm.p.lcnt[col[e] >> 7], 1);
    }
    __syncthreads();
    // block-wide exclusive scan of lcnt[0..NCMAX), 4 entries/thread
    int c4[4];
    int sum = 0;
    #pragma unroll
    for (int i = 0; i < 4; ++i) {
        int idx = t * 4 + i;
        int v = (idx < NCMAX) ? sm.p.lcnt[idx] : 0;
        c4[i] = sum; sum += v;
    }
    int incl = wave_incl_scan(sum, lane);
    int excl = incl - sum;
    if (lane == 63) sm.p.wsum[wid] = incl;
    __syncthreads();
    if (t == 0) {
        int r = 0;
        #pragma unroll
        for (int w = 0; w < 4; ++w) { int s = sm.p.wsum[w]; sm.p.woff[w] = r; r += s; }
    }
    __syncthreads();
    int tb = sm.p.woff[wid] + excl;
    __syncthreads();
    #pragma unroll
    for (int i = 0; i < 4; ++i) {
        int idx = t * 4 + i;
        if (idx < NCMAX) {
            int b0 = tb + c4[i];
            int gb = 0;
            if (idx < NC) {
                int g = idx * NBLK + blk;
                gb = histg[g] + boff[g >> SCAN_SHIFT];  // scan3 folded
            }
            sm.p.gadj[idx] = gb - b0;
            sm.p.lcnt[idx] = b0;
        }
    }
    __syncthreads();
    // pass B: scatter into LDS by bucket
    #pragma unroll
    for (int i = 0; i < CHUNK / 256; ++i) {
        int e = base + i * 256 + t;
        if (e < E) {
            int c = col[e];
            int slot = atomicAdd(&sm.p.lcnt[c >> 7], 1);
            sm.p.stage[slot] = make_int2(((c & 127) << 17) | row[e], __float_as_int(wgt[e]));
            sm.p.sdst[slot] = sm.p.gadj[c >> 7] + slot;
        }
    }
    __syncthreads();
    for (int s_ = t; s_ < nE; s_ += 256) {
        srw[sm.p.sdst[s_]] = sm.p.stage[s_];
    }
}

// ---- fine: exact CSR within each 128-node bucket + dis + spack + gemm riders ----
__global__ __launch_bounds__(256) void k_fine(const int* __restrict__ histg,
                                              const int* __restrict__ boff,
                                              const int2* __restrict__ srw,
                                              int* __restrict__ rowptr,
                                              float* __restrict__ dis,
                                              int2* __restrict__ spack,
                                              const float* __restrict__ x,
                                              const unsigned short* __restrict__ Wtg,
                                              unsigned short* __restrict__ h,
                                              int E, int N, int NC, int NBLK, int gbase) {
    __shared__ union {
        struct { int2 sbuf[3072]; int cnt128[128]; float degf[128];
                 int cur128[128]; int wtot[2]; } f;   // 25.7 KB
        GSmem g;                                      // 27.6 KB
    } sm;
    int t = threadIdx.x;
    if ((int)blockIdx.x >= NC) {  // gemm rider
        gemm_body(sm.g, x, Wtg, h, (gbase + (int)blockIdx.x - NC) * 64, N, t);
        return;
    }
    int b = blockIdx.x;
    int nb = b << 7;
    int g0 = b * NBLK;
    int start = histg[g0] + boff[g0 >> SCAN_SHIFT];
    int end;
    if (b == NC - 1) end = E;
    else {
        int g1 = (b + 1) * NBLK;
        end = histg[g1] + boff[g1 >> SCAN_SHIFT];
    }
    int cnt = end - start;
    int NL = min(cnt, 3072);
    if (t < 128) { sm.f.cnt128[t] = 0; sm.f.degf[t] = 1.0f; }  // 1.0 = self-loop
    __syncthreads();
    // phase 1: single global read; stage first NL entries into LDS
    for (int j = t; j < cnt; j += 256) {
        int2 s = srw[start + j];
        if (j < NL) sm.f.sbuf[j] = s;
        int c = s.x >> 17;
        atomicAdd(&sm.f.cnt128[c], 1);
        atomicAdd(&sm.f.degf[c], __int_as_float(s.y));
    }
    __syncthreads();
    // phase 2: 128-entry exclusive scan, write rowptr/dis, seed cursors
    int v = 0, incl = 0;
    if (t < 128) {
        v = sm.f.cnt128[t];
        incl = wave_incl_scan(v, t & 63);
        if ((t & 63) == 63) sm.f.wtot[t >> 6] = incl;
    }
    __syncthreads();
    if (t < 128) {
        int excl = incl - v + ((t >= 64) ? sm.f.wtot[0] : 0);
        int p = start + excl;
        sm.f.cur128[t] = p;
        int n = nb + t;
        if (n < N) {
            rowptr[n] = p;
            dis[n] = rsqrtf(sm.f.degf[t]);
        }
    }
    if (t == 0 && b == NC - 1) rowptr[N] = E;
    __syncthreads();
    // phase 3: final placement from LDS (global for rare overflow)
    for (int j = t; j < cnt; j += 256) {
        int2 s = (j < NL) ? sm.f.sbuf[j] : srw[start + j];
        int c = s.x >> 17;
        int pos = atomicAdd(&sm.f.cur128[c], 1);
        spack[pos] = make_int2(s.x & 0x1FFFF, s.y);
    }
}

// ---- gather: R9/R4 1-wave-per-node, unroll-8 + pipelined spack (unchanged) ----
__global__ __launch_bounds__(256) void k_gather(const unsigned int* __restrict__ hb,
                                                const float* __restrict__ dis,
                                                const int* __restrict__ rowptr,
                                                const long* __restrict__ spackl,
                                                const float* __restrict__ bias,
                                                float* __restrict__ out, int N) {
    int gid = blockIdx.x * blockDim.x + threadIdx.x;
    int node = gid >> 6;
    int lane = gid & 63;
    if (node >= N) return;
    node = __builtin_amdgcn_readfirstlane(node);

    float dn = dis[node];
    unsigned u = hb[(size_t)node * 64 + lane];
    float2 acc;
    acc.x = dn * bf_lo(u);
    acc.y = dn * bf_hi(u);

    int jb = rowptr[node], je = rowptr[node + 1];
    int j = jb;
    long q0, q1, q2, q3, q4, q5, q6, q7;
    if (j + 8 <= je) {
        q0 = __builtin_nontemporal_load(spackl + j);
        q1 = __builtin_nontemporal_load(spackl + j + 1);
        q2 = __builtin_nontemporal_load(spackl + j + 2);
        q3 = __builtin_nontemporal_load(spackl + j + 3);
        q4 = __builtin_nontemporal_load(spackl + j + 4);
        q5 = __builtin_nontemporal_load(spackl + j + 5);
        q6 = __builtin_nontemporal_load(spackl + j + 6);
        q7 = __builtin_nontemporal_load(spackl + j + 7);
    }
    for (; j + 8 <= je; j += 8) {
        int r0 = __builtin_amdgcn_readfirstlane((int)q0);
        int r1 = __builtin_amdgcn_readfirstlane((int)q1);
        int r2 = __builtin_amdgcn_readfirstlane((int)q2);
        int r3 = __builtin_amdgcn_readfirstlane((int)q3);
        int r4 = __builtin_amdgcn_readfirstlane((int)q4);
        int r5 = __builtin_amdgcn_readfirstlane((int)q5);
        int r6 = __builtin_amdgcn_readfirstlane((int)q6);
        int r7 = __builtin_amdgcn_readfirstlane((int)q7);
        unsigned u0 = hb[(size_t)r0 * 64 + lane];
        unsigned u1 = hb[(size_t)r1 * 64 + lane];
        unsigned u2 = hb[(size_t)r2 * 64 + lane];
        unsigned u3 = hb[(size_t)r3 * 64 + lane];
        unsigned u4 = hb[(size_t)r4 * 64 + lane];
        unsigned u5 = hb[(size_t)r5 * 64 + lane];
        unsigned u6 = hb[(size_t)r6 * 64 + lane];
        unsigned u7 = hb[(size_t)r7 * 64 + lane];
        int jn = (j + 16 <= je) ? j + 8 : j;
        long n0 = __builtin_nontemporal_load(spackl + jn);
        long n1 = __builtin_nontemporal_load(spackl + jn + 1);
        long n2 = __builtin_nontemporal_load(spackl + jn + 2);
        long n3 = __builtin_nontemporal_load(spackl + jn + 3);
        long n4 = __builtin_nontemporal_load(spackl + jn + 4);
        long n5 = __builtin_nontemporal_load(spackl + jn + 5);
        long n6 = __builtin_nontemporal_load(spackl + jn + 6);
        long n7 = __builtin_nontemporal_load(spackl + jn + 7);
        float a0 = dis[r0] * __uint_as_float((unsigned)((unsigned long)q0 >> 32));
        float a1 = dis[r1] * __uint_as_float((unsigned)((unsigned long)q1 >> 32));
        float a2 = dis[r2] * __uint_as_float((unsigned)((unsigned long)q2 >> 32));
        float a3 = dis[r3] * __uint_as_float((unsigned)((unsigned long)q3 >> 32));
        float a4 = dis[r4] * __uint_as_float((unsigned)((unsigned long)q4 >> 32));
        float a5 = dis[r5] * __uint_as_float((unsigned)((unsigned long)q5 >> 32));
        float a6 = dis[r6] * __uint_as_float((unsigned)((unsigned long)q6 >> 32));
        float a7 = dis[r7] * __uint_as_float((unsigned)((unsigned long)q7 >> 32));
        acc.x = fmaf(a0, bf_lo(u0), acc.x); acc.y = fmaf(a0, bf_hi(u0), acc.y);
        acc.x = fmaf(a1, bf_lo(u1), acc.x); acc.y = fmaf(a1, bf_hi(u1), acc.y);
        acc.x = fmaf(a2, bf_lo(u2), acc.x); acc.y = fmaf(a2, bf_hi(u2), acc.y);
        acc.x = fmaf(a3, bf_lo(u3), acc.x); acc.y = fmaf(a3, bf_hi(u3), acc.y);
        acc.x = fmaf(a4, bf_lo(u4), acc.x); acc.y = fmaf(a4, bf_hi(u4), acc.y);
        acc.x = fmaf(a5, bf_lo(u5), acc.x); acc.y = fmaf(a5, bf_hi(u5), acc.y);
        acc.x = fmaf(a6, bf_lo(u6), acc.x); acc.y = fmaf(a6, bf_hi(u6), acc.y);
        acc.x = fmaf(a7, bf_lo(u7), acc.x); acc.y = fmaf(a7, bf_hi(u7), acc.y);
        q0 = n0; q1 = n1; q2 = n2; q3 = n3; q4 = n4; q5 = n5; q6 = n6; q7 = n7;
    }
    for (; j < je; ++j) {
        long q = __builtin_nontemporal_load(spackl + j);
        int r = __builtin_amdgcn_readfirstlane((int)q);
        unsigned uu = hb[(size_t)r * 64 + lane];
        float a = dis[r] * __uint_as_float((unsigned)((unsigned long)q >> 32));
        acc.x = fmaf(a, bf_lo(uu), acc.x);
        acc.y = fmaf(a, bf_hi(uu), acc.y);
    }

    int c0 = lane * 2;
    float2 bv = *(const float2*)(bias + c0);
    float2 o;
    o.x = bv.x + dn * acc.x;
    o.y = bv.y + dn * acc.y;
    union { float2 f; double d; } cvt;
    cvt.f = o;
    __builtin_nontemporal_store(cvt.d, (double*)(out + (size_t)node * 128 + c0));
}

extern "C" void kernel_launch(void* const* d_in, const int* in_sizes, int n_in,
                              void* d_out, int out_size, void* d_ws, size_t ws_size,
                              hipStream_t stream) {
    const float* x     = (const float*)d_in[0];
    const int*   eidx  = (const int*)d_in[1];   // [2,E] int32
    const float* eattr = (const float*)d_in[2];
    const float* W     = (const float*)d_in[3];
    const float* bias  = (const float*)d_in[4];
    int N = in_sizes[0] / 128;
    int E = in_sizes[2];
    const int* row = eidx;
    const int* col = eidx + E;

    int NC = (N + 127) >> 7;                       // 782 coarse buckets
    int NBLK = (E + CHUNK - 1) / CHUNK;            // 782 hist/place blocks

    char* p = (char*)d_ws;
    auto carve = [&](size_t bytes) {
        char* q = p;
        p += (bytes + 255) & ~(size_t)255;
        return q;
    };
    unsigned short* h   = (unsigned short*)carve((size_t)N * 128 * sizeof(unsigned short));
    unsigned short* Wtg = (unsigned short*)carve(128 * 128 * sizeof(unsigned short));
    float* dis    = (float*)carve((size_t)N * sizeof(float));
    int*   rowptr = (int*)carve((size_t)(N + 1) * sizeof(int));
    int*   histg  = (int*)carve((size_t)NC * NBLK * sizeof(int));
    int2*  srw    = (int2*)carve((size_t)E * sizeof(int2));
    int2*  spack  = (int2*)carve((size_t)E * sizeof(int2));
    int*   bsum   = (int*)carve(256 * sizeof(int));
    int*   boff   = (int*)carve(256 * sizeof(int));

    int M = NC * NBLK;
    int NBs = (M + ELEMS_PER_SCAN_BLOCK - 1) / ELEMS_PER_SCAN_BLOCK;  // 150 <= 256
    int GB = (N + 63) / 64;   // 1563 gemm blocks
    int GBa = GB / 4;         // ride scan1
    int GBb = GB / 4;         // ride scan2
    int GBc = GB / 4;         // ride place
    int GBd = GB - GBa - GBb - GBc;  // ride fine

    k_wprep<<<128, 128, 0, stream>>>(W, Wtg);
    k_hist<<<NBLK, 256, 0, stream>>>(col, histg, E, NC, NBLK);
    k_scan1<<<NBs + GBa, 256, 0, stream>>>(histg, histg, bsum, M,
                                           x, Wtg, h, N, NBs, 0);
    k_scan2<<<1 + GBb, 256, 0, stream>>>(bsum, boff, NBs,
                                         x, Wtg, h, N, GBa);
    k_pg<<<NBLK + GBc, 256, 0, stream>>>(row, col, eattr, histg, boff, srw,
                                         x, Wtg, h, E, N, NC, NBLK, GBa + GBb);
    k_fine<<<NC + GBd, 256, 0, stream>>>(histg, boff, srw, rowptr, dis, spack,
                                         x, Wtg, h, E, N, NC, NBLK, GBa + GBb + GBc);
    {
        size_t threads = (size_t)N * 64;
        int blocks = (int)((threads + 255) / 256);
        k_gather<<<blocks, 256, 0, stream>>>((const unsigned int*)h, dis, rowptr,
                                             (const long*)spack, bias, (float*)d_out, N);
    }
}

// Round 10
// 255.167 us; speedup vs baseline: 1.0131x; 1.0131x over previous
//
#include <hip/hip_runtime.h>

// GCNConv: out = D^-1/2 (A+I) D^-1/2 X W + b
// N=100000, E=1600000, Din=Dout=128; x/W/b fp32, edge_index int32, out fp32.
//
// R14 = R12 (248.5us) with riders split across the two WIDE dispatches.
//   R13 lesson: riders on small serial dispatches (scan1/scan2) stretch the
//   critical path. Riders are only free on hosts with >= rider-chunk work.
//   - k_wprep standalone (3us) so Wtg is ready before any rider.
//   - k_hist + ~780 gemm riders (hist is 782 mem-bound blocks, ~20us host).
//   - scans pure (R12 form).
//   - k_pg + ~783 riders (782+783 ~ one occupancy window, no serial tail).
//   - k_fine pure (R12 form).
//   - k_gather: exact R4 loop (no spack prefetch; R4 73.6 < R8 74.4).

#define ELEMS_PER_SCAN_BLOCK 4096  // 256 threads * 16
#define SCAN_SHIFT 12
#define CHUNK 2048                 // edges per hist/place block
#define NCMAX 800                  // >= NC = ceil(N/128) = 782

typedef __attribute__((ext_vector_type(8))) short short8;
typedef __attribute__((ext_vector_type(4))) float f32x4;

__device__ inline unsigned short f2bf(float f) {  // fp32 -> bf16 RNE
    unsigned u = __float_as_uint(f);
    u += 0x7fffu + ((u >> 16) & 1u);
    return (unsigned short)(u >> 16);
}
__device__ inline float bf_lo(unsigned u) { return __uint_as_float(u << 16); }
__device__ inline float bf_hi(unsigned u) { return __uint_as_float(u & 0xffff0000u); }

// ---- W transpose + bf16 convert (micro-kernel, runs first) ----
__global__ void k_wprep(const float* __restrict__ W, unsigned short* __restrict__ Wtg) {
    int n = blockIdx.x;
    int k = threadIdx.x;
    Wtg[n * 128 + k] = f2bf(W[k * 128 + n]);
}

__device__ inline int wave_incl_scan(int x, int lane) {
    #pragma unroll
    for (int d = 1; d < 64; d <<= 1) {
        int y = __shfl_up(x, d, 64);
        if (lane >= d) x += y;
    }
    return x;
}

// ---- gemm smem (K-split halves): 27.6KB ----
struct GSmem { short Xs[64][72]; short Ws[128][72]; };  // 144B rows: 16B-aligned

__device__ __forceinline__ void gemm_body(GSmem& sm, const float* __restrict__ x,
                                          const unsigned short* __restrict__ Wtg,
                                          unsigned short* __restrict__ h,
                                          int row0, int N, int t) {
    int lane = t & 63, wid = t >> 6;
    int q = lane >> 4;
    int m = lane & 15;
    f32x4 acc[8];
    #pragma unroll
    for (int tde = 0; tde < 8; ++tde) acc[tde] = (f32x4){0.f, 0.f, 0.f, 0.f};

    #pragma unroll
    for (int kh = 0; kh < 2; ++kh) {
        {   // X half: 64 rows x 64 K; 16 floats/thread
            int r = t >> 2;
            int kf = (t & 3) * 16;
            int gr = row0 + r;
            const float4* src = (const float4*)(x + (size_t)gr * 128 + kh * 64 + kf);
            float4 a0 = make_float4(0.f, 0.f, 0.f, 0.f), a1 = a0, a2 = a0, a3 = a0;
            if (gr < N) { a0 = src[0]; a1 = src[1]; a2 = src[2]; a3 = src[3]; }
            short8 p0, p1;
            p0[0] = (short)f2bf(a0.x); p0[1] = (short)f2bf(a0.y);
            p0[2] = (short)f2bf(a0.z); p0[3] = (short)f2bf(a0.w);
            p0[4] = (short)f2bf(a1.x); p0[5] = (short)f2bf(a1.y);
            p0[6] = (short)f2bf(a1.z); p0[7] = (short)f2bf(a1.w);
            p1[0] = (short)f2bf(a2.x); p1[1] = (short)f2bf(a2.y);
            p1[2] = (short)f2bf(a2.z); p1[3] = (short)f2bf(a2.w);
            p1[4] = (short)f2bf(a3.x); p1[5] = (short)f2bf(a3.y);
            p1[6] = (short)f2bf(a3.z); p1[7] = (short)f2bf(a3.w);
            *(short8*)&sm.Xs[r][kf]     = p0;
            *(short8*)&sm.Xs[r][kf + 8] = p1;
        }
        {   // W half: 128 rows x 64 K; 32 shorts/thread
            int n = t >> 1;
            int off = (t & 1) * 32;
            const short* wsrc = (const short*)Wtg + n * 128 + kh * 64 + off;
            #pragma unroll
            for (int i = 0; i < 4; ++i)
                *(short8*)&sm.Ws[n][off + 8 * i] = *(const short8*)(wsrc + 8 * i);
        }
        __syncthreads();
        #pragma unroll
        for (int kc = 0; kc < 64; kc += 32) {
            short8 af = *(const short8*)&sm.Xs[wid * 16 + m][kc + q * 8];
            #pragma unroll
            for (int tde = 0; tde < 8; ++tde) {
                short8 bf = *(const short8*)&sm.Ws[tde * 16 + m][kc + q * 8];
                acc[tde] = __builtin_amdgcn_mfma_f32_16x16x32_bf16(af, bf, acc[tde], 0, 0, 0);
            }
        }
        __syncthreads();
    }
    #pragma unroll
    for (int r = 0; r < 4; ++r) {
        int grow = row0 + wid * 16 + q * 4 + r;
        if (grow < N) {
            #pragma unroll
            for (int tde = 0; tde < 8; ++tde)
                h[(size_t)grow * 128 + tde * 16 + m] = f2bf(acc[tde][r]);
        }
    }
}

// ---- coarse histogram + gemm riders ----
__global__ __launch_bounds__(256) void k_hist(const int* __restrict__ col,
                                              int* __restrict__ histg,
                                              const float* __restrict__ x,
                                              const unsigned short* __restrict__ Wtg,
                                              unsigned short* __restrict__ h,
                                              int E, int N, int NC, int NBLK, int gbase) {
    __shared__ union { int lh[1024]; GSmem g; } sm;
    int t = threadIdx.x;
    if ((int)blockIdx.x >= NBLK) {  // gemm rider
        gemm_body(sm.g, x, Wtg, h, (gbase + (int)blockIdx.x - NBLK) * 64, N, t);
        return;
    }
    int blk = blockIdx.x;
    for (int i = t; i < 1024; i += 256) sm.lh[i] = 0;
    __syncthreads();
    int base = blk * CHUNK;
    #pragma unroll
    for (int i = 0; i < CHUNK / 256; ++i) {
        int e = base + i * 256 + t;
        if (e < E) atomicAdd(&sm.lh[col[e] >> 7], 1);
    }
    __syncthreads();
    for (int b = t; b < NC; b += 256) histg[b * NBLK + blk] = sm.lh[b];
}

// ---- scans (pure, R12 form) ----
__global__ void k_scan1(const int* __restrict__ in, int* __restrict__ out,
                        int* __restrict__ bsum, int M) {
    __shared__ int wsum[4];
    __shared__ int woff[4];
    int t = threadIdx.x, lane = t & 63, wid = t >> 6;
    int base = blockIdx.x * ELEMS_PER_SCAN_BLOCK + t * 16;
    int v[16];
    #pragma unroll
    for (int i = 0; i < 16; ++i) v[i] = (base + i < M) ? in[base + i] : 0;
    int run = 0;
    #pragma unroll
    for (int i = 0; i < 16; ++i) { int x = v[i]; v[i] = run; run += x; }
    int incl = wave_incl_scan(run, lane);
    int excl = incl - run;
    if (lane == 63) wsum[wid] = incl;
    __syncthreads();
    if (t == 0) {
        int r = 0;
        #pragma unroll
        for (int w = 0; w < 4; ++w) { int s = wsum[w]; woff[w] = r; r += s; }
        bsum[blockIdx.x] = r;
    }
    __syncthreads();
    int off = woff[wid] + excl;
    #pragma unroll
    for (int i = 0; i < 16; ++i)
        if (base + i < M) out[base + i] = v[i] + off;
}

__global__ void k_scan2(const int* __restrict__ bsum, int* __restrict__ boff, int NB) {
    __shared__ int wsum[4];
    __shared__ int woff[4];
    int t = threadIdx.x, lane = t & 63, wid = t >> 6;
    int x = (t < NB) ? bsum[t] : 0;
    int incl = wave_incl_scan(x, lane);
    int excl = incl - x;
    if (lane == 63) wsum[wid] = incl;
    __syncthreads();
    if (t == 0) {
        int r = 0;
        #pragma unroll
        for (int w = 0; w < 4; ++w) { int s = wsum[w]; woff[w] = r; r += s; }
    }
    __syncthreads();
    if (t < NB) boff[t] = woff[wid] + excl;
}

// ---- fused: place (blocks [0,NBLK)) + gemm riders ----
__global__ __launch_bounds__(256) void k_pg(const int* __restrict__ row,
                                            const int* __restrict__ col,
                                            const float* __restrict__ wgt,
                                            const int* __restrict__ histg,
                                            const int* __restrict__ boff,
                                            int2* __restrict__ srw,
                                            const float* __restrict__ x,
                                            const unsigned short* __restrict__ Wtg,
                                            unsigned short* __restrict__ h,
                                            int E, int N, int NC, int NBLK, int gbase) {
    __shared__ union {
        struct { int lcnt[NCMAX]; int gadj[NCMAX]; int2 stage[CHUNK]; int sdst[CHUNK];
                 int wsum[4]; int woff[4]; } p;   // 30.0 KB
        GSmem g;                                  // 27.6 KB
    } sm;
    int t = threadIdx.x;
    if ((int)blockIdx.x >= NBLK) {  // gemm rider
        gemm_body(sm.g, x, Wtg, h, (gbase + (int)blockIdx.x - NBLK) * 64, N, t);
        return;
    }
    int blk = blockIdx.x;
    int lane = t & 63, wid = t >> 6;
    int base = blk * CHUNK;
    int nE = min(CHUNK, E - base);
    for (int b = t; b < NCMAX; b += 256) sm.p.lcnt[b] = 0;
    __syncthreads();
    // pass A: local count
    #pragma unroll
    for (int i = 0; i < CHUNK / 256; ++i) {
        int e = base + i * 256 + t;
        if (e < E) atomicAdd(&sm.p.lcnt[col[e] >> 7], 1);
    }
    __syncthreads();
    // block-wide exclusive scan of lcnt[0..NCMAX), 4 entries/thread
    int c4[4];
    int sum = 0;
    #pragma unroll
    for (int i = 0; i < 4; ++i) {
        int idx = t * 4 + i;
        int v = (idx < NCMAX) ? sm.p.lcnt[idx] : 0;
        c4[i] = sum; sum += v;
    }
    int incl = wave_incl_scan(sum, lane);
    int excl = incl - sum;
    if (lane == 63) sm.p.wsum[wid] = incl;
    __syncthreads();
    if (t == 0) {
        int r = 0;
        #pragma unroll
        for (int w = 0; w < 4; ++w) { int s = sm.p.wsum[w]; sm.p.woff[w] = r; r += s; }
    }
    __syncthreads();
    int tb = sm.p.woff[wid] + excl;
    __syncthreads();
    #pragma unroll
    for (int i = 0; i < 4; ++i) {
        int idx = t * 4 + i;
        if (idx < NCMAX) {
            int b0 = tb + c4[i];
            int gb = 0;
            if (idx < NC) {
                int g = idx * NBLK + blk;
                gb = histg[g] + boff[g >> SCAN_SHIFT];  // scan3 folded
            }
            sm.p.gadj[idx] = gb - b0;
            sm.p.lcnt[idx] = b0;
        }
    }
    __syncthreads();
    // pass B: scatter into LDS by bucket
    #pragma unroll
    for (int i = 0; i < CHUNK / 256; ++i) {
        int e = base + i * 256 + t;
        if (e < E) {
            int c = col[e];
            int slot = atomicAdd(&sm.p.lcnt[c >> 7], 1);
            sm.p.stage[slot] = make_int2(((c & 127) << 17) | row[e], __float_as_int(wgt[e]));
            sm.p.sdst[slot] = sm.p.gadj[c >> 7] + slot;
        }
    }
    __syncthreads();
    for (int s_ = t; s_ < nE; s_ += 256) {
        srw[sm.p.sdst[s_]] = sm.p.stage[s_];
    }
}

// ---- fine: exact CSR within each 128-node bucket + dis + spack (pure) ----
__global__ __launch_bounds__(256) void k_fine(const int* __restrict__ histg,
                                              const int* __restrict__ boff,
                                              const int2* __restrict__ srw,
                                              int* __restrict__ rowptr,
                                              float* __restrict__ dis,
                                              int2* __restrict__ spack,
                                              int E, int N, int NC, int NBLK) {
    __shared__ struct { int2 sbuf[3072]; int cnt128[128]; float degf[128];
                        int cur128[128]; int wtot[2]; } sf;   // 25.7 KB
    int t = threadIdx.x, b = blockIdx.x;
    int nb = b << 7;
    int g0 = b * NBLK;
    int start = histg[g0] + boff[g0 >> SCAN_SHIFT];
    int end;
    if (b == NC - 1) end = E;
    else {
        int g1 = (b + 1) * NBLK;
        end = histg[g1] + boff[g1 >> SCAN_SHIFT];
    }
    int cnt = end - start;
    int NL = min(cnt, 3072);
    if (t < 128) { sf.cnt128[t] = 0; sf.degf[t] = 1.0f; }  // 1.0 = self-loop
    __syncthreads();
    // phase 1: single global read; stage first NL entries into LDS
    for (int j = t; j < cnt; j += 256) {
        int2 s = srw[start + j];
        if (j < NL) sf.sbuf[j] = s;
        int c = s.x >> 17;
        atomicAdd(&sf.cnt128[c], 1);
        atomicAdd(&sf.degf[c], __int_as_float(s.y));
    }
    __syncthreads();
    // phase 2: 128-entry exclusive scan, write rowptr/dis, seed cursors
    int v = 0, incl = 0;
    if (t < 128) {
        v = sf.cnt128[t];
        incl = wave_incl_scan(v, t & 63);
        if ((t & 63) == 63) sf.wtot[t >> 6] = incl;
    }
    __syncthreads();
    if (t < 128) {
        int excl = incl - v + ((t >= 64) ? sf.wtot[0] : 0);
        int p = start + excl;
        sf.cur128[t] = p;
        int n = nb + t;
        if (n < N) {
            rowptr[n] = p;
            dis[n] = rsqrtf(sf.degf[t]);
        }
    }
    if (t == 0 && b == NC - 1) rowptr[N] = E;
    __syncthreads();
    // phase 3: final placement from LDS (global for rare overflow)
    for (int j = t; j < cnt; j += 256) {
        int2 s = (j < NL) ? sf.sbuf[j] : srw[start + j];
        int c = s.x >> 17;
        int pos = atomicAdd(&sf.cur128[c], 1);
        spack[pos] = make_int2(s.x & 0x1FFFF, s.y);
    }
}

// ---- gather: exact R4 loop (unroll-8 + scalar tail, no prefetch) ----
__global__ __launch_bounds__(256) void k_gather(const unsigned int* __restrict__ hb,
                                                const float* __restrict__ dis,
                                                const int* __restrict__ rowptr,
                                                const long* __restrict__ spackl,
                                                const float* __restrict__ bias,
                                                float* __restrict__ out, int N) {
    int gid = blockIdx.x * blockDim.x + threadIdx.x;
    int node = gid >> 6;
    int lane = gid & 63;
    if (node >= N) return;
    node = __builtin_amdgcn_readfirstlane(node);

    float dn = dis[node];
    unsigned u = hb[(size_t)node * 64 + lane];
    float2 acc;
    acc.x = dn * bf_lo(u);
    acc.y = dn * bf_hi(u);

    int jb = rowptr[node], je = rowptr[node + 1];
    int j = jb;
    for (; j + 8 <= je; j += 8) {   // 8 h-rows in flight
        long q0 = __builtin_nontemporal_load(spackl + j);
        long q1 = __builtin_nontemporal_load(spackl + j + 1);
        long q2 = __builtin_nontemporal_load(spackl + j + 2);
        long q3 = __builtin_nontemporal_load(spackl + j + 3);
        long q4 = __builtin_nontemporal_load(spackl + j + 4);
        long q5 = __builtin_nontemporal_load(spackl + j + 5);
        long q6 = __builtin_nontemporal_load(spackl + j + 6);
        long q7 = __builtin_nontemporal_load(spackl + j + 7);
        int r0 = __builtin_amdgcn_readfirstlane((int)q0);
        int r1 = __builtin_amdgcn_readfirstlane((int)q1);
        int r2 = __builtin_amdgcn_readfirstlane((int)q2);
        int r3 = __builtin_amdgcn_readfirstlane((int)q3);
        int r4 = __builtin_amdgcn_readfirstlane((int)q4);
        int r5 = __builtin_amdgcn_readfirstlane((int)q5);
        int r6 = __builtin_amdgcn_readfirstlane((int)q6);
        int r7 = __builtin_amdgcn_readfirstlane((int)q7);
        unsigned u0 = hb[(size_t)r0 * 64 + lane];
        unsigned u1 = hb[(size_t)r1 * 64 + lane];
        unsigned u2 = hb[(size_t)r2 * 64 + lane];
        unsigned u3 = hb[(size_t)r3 * 64 + lane];
        unsigned u4 = hb[(size_t)r4 * 64 + lane];
        unsigned u5 = hb[(size_t)r5 * 64 + lane];
        unsigned u6 = hb[(size_t)r6 * 64 + lane];
        unsigned u7 = hb[(size_t)r7 * 64 + lane];
        float a0 = dis[r0] * __uint_as_float((unsigned)((unsigned long)q0 >> 32));
        float a1 = dis[r1] * __uint_as_float((unsigned)((unsigned long)q1 >> 32));
        float a2 = dis[r2] * __uint_as_float((unsigned)((unsigned long)q2 >> 32));
        float a3 = dis[r3] * __uint_as_float((unsigned)((unsigned long)q3 >> 32));
        float a4 = dis[r4] * __uint_as_float((unsigned)((unsigned long)q4 >> 32));
        float a5 = dis[r5] * __uint_as_float((unsigned)((unsigned long)q5 >> 32));
        float a6 = dis[r6] * __uint_as_float((unsigned)((unsigned long)q6 >> 32));
        float a7 = dis[r7] * __uint_as_float((unsigned)((unsigned long)q7 >> 32));
        acc.x = fmaf(a0, bf_lo(u0), acc.x); acc.y = fmaf(a0, bf_hi(u0), acc.y);
        acc.x = fmaf(a1, bf_lo(u1), acc.x); acc.y = fmaf(a1, bf_hi(u1), acc.y);
        acc.x = fmaf(a2, bf_lo(u2), acc.x); acc.y = fmaf(a2, bf_hi(u2), acc.y);
        acc.x = fmaf(a3, bf_lo(u3), acc.x); acc.y = fmaf(a3, bf_hi(u3), acc.y);
        acc.x = fmaf(a4, bf_lo(u4), acc.x); acc.y = fmaf(a4, bf_hi(u4), acc.y);
        acc.x = fmaf(a5, bf_lo(u5), acc.x); acc.y = fmaf(a5, bf_hi(u5), acc.y);
        acc.x = fmaf(a6, bf_lo(u6), acc.x); acc.y = fmaf(a6, bf_hi(u6), acc.y);
        acc.x = fmaf(a7, bf_lo(u7), acc.x); acc.y = fmaf(a7, bf_hi(u7), acc.y);
    }
    for (; j < je; ++j) {
        long q = __builtin_nontemporal_load(spackl + j);
        int r = __builtin_amdgcn_readfirstlane((int)q);
        unsigned uu = hb[(size_t)r * 64 + lane];
        float a = dis[r] * __uint_as_float((unsigned)((unsigned long)q >> 32));
        acc.x = fmaf(a, bf_lo(uu), acc.x);
        acc.y = fmaf(a, bf_hi(uu), acc.y);
    }

    int c0 = lane * 2;
    float2 bv = *(const float2*)(bias + c0);
    float2 o;
    o.x = bv.x + dn * acc.x;
    o.y = bv.y + dn * acc.y;
    union { float2 f; double d; } cvt;
    cvt.f = o;
    __builtin_nontemporal_store(cvt.d, (double*)(out + (size_t)node * 128 + c0));
}

extern "C" void kernel_launch(void* const* d_in, const int* in_sizes, int n_in,
                              void* d_out, int out_size, void* d_ws, size_t ws_size,
                              hipStream_t stream) {
    const float* x     = (const float*)d_in[0];
    const int*   eidx  = (const int*)d_in[1];   // [2,E] int32
    const float* eattr = (const float*)d_in[2];
    const float* W     = (const float*)d_in[3];
    const float* bias  = (const float*)d_in[4];
    int N = in_sizes[0] / 128;
    int E = in_sizes[2];
    const int* row = eidx;
    const int* col = eidx + E;

    int NC = (N + 127) >> 7;                       // 782 coarse buckets
    int NBLK = (E + CHUNK - 1) / CHUNK;            // 782 hist/place blocks

    char* p = (char*)d_ws;
    auto carve = [&](size_t bytes) {
        char* q = p;
        p += (bytes + 255) & ~(size_t)255;
        return q;
    };
    unsigned short* h   = (unsigned short*)carve((size_t)N * 128 * sizeof(unsigned short));
    unsigned short* Wtg = (unsigned short*)carve(128 * 128 * sizeof(unsigned short));
    float* dis    = (float*)carve((size_t)N * sizeof(float));
    int*   rowptr = (int*)carve((size_t)(N + 1) * sizeof(int));
    int*   histg  = (int*)carve((size_t)NC * NBLK * sizeof(int));
    int2*  srw    = (int2*)carve((size_t)E * sizeof(int2));
    int2*  spack  = (int2*)carve((size_t)E * sizeof(int2));
    int*   bsum   = (int*)carve(256 * sizeof(int));
    int*   boff   = (int*)carve(256 * sizeof(int));

    int M = NC * NBLK;
    int NBs = (M + ELEMS_PER_SCAN_BLOCK - 1) / ELEMS_PER_SCAN_BLOCK;  // 150 <= 256
    int GB  = (N + 63) / 64;   // 1563 gemm blocks
    int GB1 = GB / 2;          // ride hist
    int GB2 = GB - GB1;        // ride place

    k_wprep<<<128, 128, 0, stream>>>(W, Wtg);
    k_hist<<<NBLK + GB1, 256, 0, stream>>>(col, histg, x, Wtg, h,
                                           E, N, NC, NBLK, 0);
    k_scan1<<<NBs, 256, 0, stream>>>(histg, histg, bsum, M);
    k_scan2<<<1, 256, 0, stream>>>(bsum, boff, NBs);
    k_pg<<<NBLK + GB2, 256, 0, stream>>>(row, col, eattr, histg, boff, srw,
                                         x, Wtg, h, E, N, NC, NBLK, GB1);
    k_fine<<<NC, 256, 0, stream>>>(histg, boff, srw, rowptr, dis, spack, E, N, NC, NBLK);
    {
        size_t threads = (size_t)N * 64;
        int blocks = (int)((threads + 255) / 256);
        k_gather<<<blocks, 256, 0, stream>>>((const unsigned int*)h, dis, rowptr,
                                             (const long*)spack, bias, (float*)d_out, N);
    }
}

// Round 12
// 251.707 us; speedup vs baseline: 1.0270x; 1.0137x over previous
//
#include <hip/hip_runtime.h>

// GCNConv: out = D^-1/2 (A+I) D^-1/2 X W + b
// N=100000, E=1600000, Din=Dout=128; x/W/b fp32, edge_index int32, out fp32.
//
// R16 = R15 resubmitted verbatim (bench infra failed twice; kernel is
// composed entirely of previously-measured-passing components).
//  - gather: no-prefetch R4 loop (73.5us measured in R14's passing run).
//  - riders split 781 on pg + 782 on fine (R12 put all 1563 on pg ->
//    0.83-window serial tail while fine ran 39% empty).
//  - hist keeps wprep fold + 4KB LDS (R14 lesson: union LDS on hist
//    killed its occupancy). scans pure.

#define ELEMS_PER_SCAN_BLOCK 4096  // 256 threads * 16
#define SCAN_SHIFT 12
#define CHUNK 2048                 // edges per hist/place block
#define NCMAX 800                  // >= NC = ceil(N/128) = 782

typedef __attribute__((ext_vector_type(8))) short short8;
typedef __attribute__((ext_vector_type(4))) float f32x4;

__device__ inline unsigned short f2bf(float f) {  // fp32 -> bf16 RNE
    unsigned u = __float_as_uint(f);
    u += 0x7fffu + ((u >> 16) & 1u);
    return (unsigned short)(u >> 16);
}
__device__ inline float bf_lo(unsigned u) { return __uint_as_float(u << 16); }
__device__ inline float bf_hi(unsigned u) { return __uint_as_float(u & 0xffff0000u); }

// ---- coarse histogram + W-prep fold (4KB LDS, high occupancy) ----
__global__ __launch_bounds__(256) void k_hist(const int* __restrict__ col,
                                              const float* __restrict__ W,
                                              int* __restrict__ histg,
                                              unsigned short* __restrict__ Wtg,
                                              int E, int NC, int NBLK) {
    __shared__ int lh[1024];
    int t = threadIdx.x, blk = blockIdx.x;
    if (blk < 64) {  // W transpose+bf16: 2 rows per block
        int n = blk * 2 + (t >> 7);
        int k = t & 127;
        Wtg[n * 128 + k] = f2bf(W[k * 128 + n]);
    }
    for (int i = t; i < 1024; i += 256) lh[i] = 0;
    __syncthreads();
    int base = blk * CHUNK;
    #pragma unroll
    for (int i = 0; i < CHUNK / 256; ++i) {
        int e = base + i * 256 + t;
        if (e < E) atomicAdd(&lh[col[e] >> 7], 1);
    }
    __syncthreads();
    for (int b = t; b < NC; b += 256) histg[b * NBLK + blk] = lh[b];
}

__device__ inline int wave_incl_scan(int x, int lane) {
    #pragma unroll
    for (int d = 1; d < 64; d <<= 1) {
        int y = __shfl_up(x, d, 64);
        if (lane >= d) x += y;
    }
    return x;
}

// ---- scans (pure) ----
__global__ void k_scan1(const int* __restrict__ in, int* __restrict__ out,
                        int* __restrict__ bsum, int M) {
    __shared__ int wsum[4];
    __shared__ int woff[4];
    int t = threadIdx.x, lane = t & 63, wid = t >> 6;
    int base = blockIdx.x * ELEMS_PER_SCAN_BLOCK + t * 16;
    int v[16];
    #pragma unroll
    for (int i = 0; i < 16; ++i) v[i] = (base + i < M) ? in[base + i] : 0;
    int run = 0;
    #pragma unroll
    for (int i = 0; i < 16; ++i) { int x = v[i]; v[i] = run; run += x; }
    int incl = wave_incl_scan(run, lane);
    int excl = incl - run;
    if (lane == 63) wsum[wid] = incl;
    __syncthreads();
    if (t == 0) {
        int r = 0;
        #pragma unroll
        for (int w = 0; w < 4; ++w) { int s = wsum[w]; woff[w] = r; r += s; }
        bsum[blockIdx.x] = r;
    }
    __syncthreads();
    int off = woff[wid] + excl;
    #pragma unroll
    for (int i = 0; i < 16; ++i)
        if (base + i < M) out[base + i] = v[i] + off;
}

__global__ void k_scan2(const int* __restrict__ bsum, int* __restrict__ boff, int NB) {
    __shared__ int wsum[4];
    __shared__ int woff[4];
    int t = threadIdx.x, lane = t & 63, wid = t >> 6;
    int x = (t < NB) ? bsum[t] : 0;
    int incl = wave_incl_scan(x, lane);
    int excl = incl - x;
    if (lane == 63) wsum[wid] = incl;
    __syncthreads();
    if (t == 0) {
        int r = 0;
        #pragma unroll
        for (int w = 0; w < 4; ++w) { int s = wsum[w]; woff[w] = r; r += s; }
    }
    __syncthreads();
    if (t < NB) boff[t] = woff[wid] + excl;
}

// ---- gemm smem (K-split halves): 27.6KB ----
struct GSmem { short Xs[64][72]; short Ws[128][72]; };  // 144B rows: 16B-aligned

__device__ __forceinline__ void gemm_body(GSmem& sm, const float* __restrict__ x,
                                          const unsigned short* __restrict__ Wtg,
                                          unsigned short* __restrict__ h,
                                          int row0, int N, int t) {
    int lane = t & 63, wid = t >> 6;
    int q = lane >> 4;
    int m = lane & 15;
    f32x4 acc[8];
    #pragma unroll
    for (int tde = 0; tde < 8; ++tde) acc[tde] = (f32x4){0.f, 0.f, 0.f, 0.f};

    #pragma unroll
    for (int kh = 0; kh < 2; ++kh) {
        {   // X half: 64 rows x 64 K; 16 floats/thread
            int r = t >> 2;
            int kf = (t & 3) * 16;
            int gr = row0 + r;
            const float4* src = (const float4*)(x + (size_t)gr * 128 + kh * 64 + kf);
            float4 a0 = make_float4(0.f, 0.f, 0.f, 0.f), a1 = a0, a2 = a0, a3 = a0;
            if (gr < N) { a0 = src[0]; a1 = src[1]; a2 = src[2]; a3 = src[3]; }
            short8 p0, p1;
            p0[0] = (short)f2bf(a0.x); p0[1] = (short)f2bf(a0.y);
            p0[2] = (short)f2bf(a0.z); p0[3] = (short)f2bf(a0.w);
            p0[4] = (short)f2bf(a1.x); p0[5] = (short)f2bf(a1.y);
            p0[6] = (short)f2bf(a1.z); p0[7] = (short)f2bf(a1.w);
            p1[0] = (short)f2bf(a2.x); p1[1] = (short)f2bf(a2.y);
            p1[2] = (short)f2bf(a2.z); p1[3] = (short)f2bf(a2.w);
            p1[4] = (short)f2bf(a3.x); p1[5] = (short)f2bf(a3.y);
            p1[6] = (short)f2bf(a3.z); p1[7] = (short)f2bf(a3.w);
            *(short8*)&sm.Xs[r][kf]     = p0;
            *(short8*)&sm.Xs[r][kf + 8] = p1;
        }
        {   // W half: 128 rows x 64 K; 32 shorts/thread
            int n = t >> 1;
            int off = (t & 1) * 32;
            const short* wsrc = (const short*)Wtg + n * 128 + kh * 64 + off;
            #pragma unroll
            for (int i = 0; i < 4; ++i)
                *(short8*)&sm.Ws[n][off + 8 * i] = *(const short8*)(wsrc + 8 * i);
        }
        __syncthreads();
        #pragma unroll
        for (int kc = 0; kc < 64; kc += 32) {
            short8 af = *(const short8*)&sm.Xs[wid * 16 + m][kc + q * 8];
            #pragma unroll
            for (int tde = 0; tde < 8; ++tde) {
                short8 bf = *(const short8*)&sm.Ws[tde * 16 + m][kc + q * 8];
                acc[tde] = __builtin_amdgcn_mfma_f32_16x16x32_bf16(af, bf, acc[tde], 0, 0, 0);
            }
        }
        __syncthreads();
    }
    #pragma unroll
    for (int r = 0; r < 4; ++r) {
        int grow = row0 + wid * 16 + q * 4 + r;
        if (grow < N) {
            #pragma unroll
            for (int tde = 0; tde < 8; ++tde)
                h[(size_t)grow * 128 + tde * 16 + m] = f2bf(acc[tde][r]);
        }
    }
}

// ---- fused: place (blocks [0,NBLK)) + gemm riders ----
__global__ __launch_bounds__(256) void k_pg(const int* __restrict__ row,
                                            const int* __restrict__ col,
                                            const float* __restrict__ wgt,
                                            const int* __restrict__ histg,
                                            const int* __restrict__ boff,
                                            int2* __restrict__ srw,
                                            const float* __restrict__ x,
                                            const unsigned short* __restrict__ Wtg,
                                            unsigned short* __restrict__ h,
                                            int E, int N, int NC, int NBLK, int gbase) {
    __shared__ union {
        struct { int lcnt[NCMAX]; int gadj[NCMAX]; int2 stage[CHUNK]; int sdst[CHUNK];
                 int wsum[4]; int woff[4]; } p;   // 30.0 KB
        GSmem g;                                  // 27.6 KB
    } sm;
    int t = threadIdx.x;
    if ((int)blockIdx.x >= NBLK) {  // gemm rider
        gemm_body(sm.g, x, Wtg, h, (gbase + (int)blockIdx.x - NBLK) * 64, N, t);
        return;
    }
    int blk = blockIdx.x;
    int lane = t & 63, wid = t >> 6;
    int base = blk * CHUNK;
    int nE = min(CHUNK, E - base);
    for (int b = t; b < NCMAX; b += 256) sm.p.lcnt[b] = 0;
    __syncthreads();
    // pass A: local count
    #pragma unroll
    for (int i = 0; i < CHUNK / 256; ++i) {
        int e = base + i * 256 + t;
        if (e < E) atomicAdd(&sm.p.lcnt[col[e] >> 7], 1);
    }
    __syncthreads();
    // block-wide exclusive scan of lcnt[0..NCMAX), 4 entries/thread
    int c4[4];
    int sum = 0;
    #pragma unroll
    for (int i = 0; i < 4; ++i) {
        int idx = t * 4 + i;
        int v = (idx < NCMAX) ? sm.p.lcnt[idx] : 0;
        c4[i] = sum; sum += v;
    }
    int incl = wave_incl_scan(sum, lane);
    int excl = incl - sum;
    if (lane == 63) sm.p.wsum[wid] = incl;
    __syncthreads();
    if (t == 0) {
        int r = 0;
        #pragma unroll
        for (int w = 0; w < 4; ++w) { int s = sm.p.wsum[w]; sm.p.woff[w] = r; r += s; }
    }
    __syncthreads();
    int tb = sm.p.woff[wid] + excl;
    __syncthreads();
    #pragma unroll
    for (int i = 0; i < 4; ++i) {
        int idx = t * 4 + i;
        if (idx < NCMAX) {
            int b0 = tb + c4[i];
            int gb = 0;
            if (idx < NC) {
                int g = idx * NBLK + blk;
                gb = histg[g] + boff[g >> SCAN_SHIFT];  // scan3 folded
            }
            sm.p.gadj[idx] = gb - b0;
            sm.p.lcnt[idx] = b0;
        }
    }
    __syncthreads();
    // pass B: scatter into LDS by bucket
    #pragma unroll
    for (int i = 0; i < CHUNK / 256; ++i) {
        int e = base + i * 256 + t;
        if (e < E) {
            int c = col[e];
            int slot = atomicAdd(&sm.p.lcnt[c >> 7], 1);
            sm.p.stage[slot] = make_int2(((c & 127) << 17) | row[e], __float_as_int(wgt[e]));
            sm.p.sdst[slot] = sm.p.gadj[c >> 7] + slot;
        }
    }
    __syncthreads();
    for (int s_ = t; s_ < nE; s_ += 256) {
        srw[sm.p.sdst[s_]] = sm.p.stage[s_];
    }
}

// ---- fine: exact CSR within each 128-node bucket + dis + spack + gemm riders ----
__global__ __launch_bounds__(256) void k_fine(const int* __restrict__ histg,
                                              const int* __restrict__ boff,
                                              const int2* __restrict__ srw,
                                              int* __restrict__ rowptr,
                                              float* __restrict__ dis,
                                              int2* __restrict__ spack,
                                              const float* __restrict__ x,
                                              const unsigned short* __restrict__ Wtg,
                                              unsigned short* __restrict__ h,
                                              int E, int N, int NC, int NBLK, int gbase) {
    __shared__ union {
        struct { int2 sbuf[3072]; int cnt128[128]; float degf[128];
                 int cur128[128]; int wtot[2]; } f;   // 25.7 KB
        GSmem g;                                      // 27.6 KB
    } sm;
    int t = threadIdx.x;
    if ((int)blockIdx.x >= NC) {  // gemm rider
        gemm_body(sm.g, x, Wtg, h, (gbase + (int)blockIdx.x - NC) * 64, N, t);
        return;
    }
    int b = blockIdx.x;
    int nb = b << 7;
    int g0 = b * NBLK;
    int start = histg[g0] + boff[g0 >> SCAN_SHIFT];
    int end;
    if (b == NC - 1) end = E;
    else {
        int g1 = (b + 1) * NBLK;
        end = histg[g1] + boff[g1 >> SCAN_SHIFT];
    }
    int cnt = end - start;
    int NL = min(cnt, 3072);
    if (t < 128) { sm.f.cnt128[t] = 0; sm.f.degf[t] = 1.0f; }  // 1.0 = self-loop
    __syncthreads();
    // phase 1: single global read; stage first NL entries into LDS
    for (int j = t; j < cnt; j += 256) {
        int2 s = srw[start + j];
        if (j < NL) sm.f.sbuf[j] = s;
        int c = s.x >> 17;
        atomicAdd(&sm.f.cnt128[c], 1);
        atomicAdd(&sm.f.degf[c], __int_as_float(s.y));
    }
    __syncthreads();
    // phase 2: 128-entry exclusive scan, write rowptr/dis, seed cursors
    int v = 0, incl = 0;
    if (t < 128) {
        v = sm.f.cnt128[t];
        incl = wave_incl_scan(v, t & 63);
        if ((t & 63) == 63) sm.f.wtot[t >> 6] = incl;
    }
    __syncthreads();
    if (t < 128) {
        int excl = incl - v + ((t >= 64) ? sm.f.wtot[0] : 0);
        int p = start + excl;
        sm.f.cur128[t] = p;
        int n = nb + t;
        if (n < N) {
            rowptr[n] = p;
            dis[n] = rsqrtf(sm.f.degf[t]);
        }
    }
    if (t == 0 && b == NC - 1) rowptr[N] = E;
    __syncthreads();
    // phase 3: final placement from LDS (global for rare overflow)
    for (int j = t; j < cnt; j += 256) {
        int2 s = (j < NL) ? sm.f.sbuf[j] : srw[start + j];
        int c = s.x >> 17;
        int pos = atomicAdd(&sm.f.cur128[c], 1);
        spack[pos] = make_int2(s.x & 0x1FFFF, s.y);
    }
}

// ---- gather: exact R4 loop (unroll-8 + scalar tail, no prefetch; 73.5us) ----
__global__ __launch_bounds__(256) void k_gather(const unsigned int* __restrict__ hb,
                                                const float* __restrict__ dis,
                                                const int* __restrict__ rowptr,
                                                const long* __restrict__ spackl,
                                                const float* __restrict__ bias,
                                                float* __restrict__ out, int N) {
    int gid = blockIdx.x * blockDim.x + threadIdx.x;
    int node = gid >> 6;
    int lane = gid & 63;
    if (node >= N) return;
    node = __builtin_amdgcn_readfirstlane(node);

    float dn = dis[node];
    unsigned u = hb[(size_t)node * 64 + lane];
    float2 acc;
    acc.x = dn * bf_lo(u);
    acc.y = dn * bf_hi(u);

    int jb = rowptr[node], je = rowptr[node + 1];
    int j = jb;
    for (; j + 8 <= je; j += 8) {   // 8 h-rows in flight
        long q0 = __builtin_nontemporal_load(spackl + j);
        long q1 = __builtin_nontemporal_load(spackl + j + 1);
        long q2 = __builtin_nontemporal_load(spackl + j + 2);
        long q3 = __builtin_nontemporal_load(spackl + j + 3);
        long q4 = __builtin_nontemporal_load(spackl + j + 4);
        long q5 = __builtin_nontemporal_load(spackl + j + 5);
        long q6 = __builtin_nontemporal_load(spackl + j + 6);
        long q7 = __builtin_nontemporal_load(spackl + j + 7);
        int r0 = __builtin_amdgcn_readfirstlane((int)q0);
        int r1 = __builtin_amdgcn_readfirstlane((int)q1);
        int r2 = __builtin_amdgcn_readfirstlane((int)q2);
        int r3 = __builtin_amdgcn_readfirstlane((int)q3);
        int r4 = __builtin_amdgcn_readfirstlane((int)q4);
        int r5 = __builtin_amdgcn_readfirstlane((int)q5);
        int r6 = __builtin_amdgcn_readfirstlane((int)q6);
        int r7 = __builtin_amdgcn_readfirstlane((int)q7);
        unsigned u0 = hb[(size_t)r0 * 64 + lane];
        unsigned u1 = hb[(size_t)r1 * 64 + lane];
        unsigned u2 = hb[(size_t)r2 * 64 + lane];
        unsigned u3 = hb[(size_t)r3 * 64 + lane];
        unsigned u4 = hb[(size_t)r4 * 64 + lane];
        unsigned u5 = hb[(size_t)r5 * 64 + lane];
        unsigned u6 = hb[(size_t)r6 * 64 + lane];
        unsigned u7 = hb[(size_t)r7 * 64 + lane];
        float a0 = dis[r0] * __uint_as_float((unsigned)((unsigned long)q0 >> 32));
        float a1 = dis[r1] * __uint_as_float((unsigned)((unsigned long)q1 >> 32));
        float a2 = dis[r2] * __uint_as_float((unsigned)((unsigned long)q2 >> 32));
        float a3 = dis[r3] * __uint_as_float((unsigned)((unsigned long)q3 >> 32));
        float a4 = dis[r4] * __uint_as_float((unsigned)((unsigned long)q4 >> 32));
        float a5 = dis[r5] * __uint_as_float((unsigned)((unsigned long)q5 >> 32));
        float a6 = dis[r6] * __uint_as_float((unsigned)((unsigned long)q6 >> 32));
        float a7 = dis[r7] * __uint_as_float((unsigned)((unsigned long)q7 >> 32));
        acc.x = fmaf(a0, bf_lo(u0), acc.x); acc.y = fmaf(a0, bf_hi(u0), acc.y);
        acc.x = fmaf(a1, bf_lo(u1), acc.x); acc.y = fmaf(a1, bf_hi(u1), acc.y);
        acc.x = fmaf(a2, bf_lo(u2), acc.x); acc.y = fmaf(a2, bf_hi(u2), acc.y);
        acc.x = fmaf(a3, bf_lo(u3), acc.x); acc.y = fmaf(a3, bf_hi(u3), acc.y);
        acc.x = fmaf(a4, bf_lo(u4), acc.x); acc.y = fmaf(a4, bf_hi(u4), acc.y);
        acc.x = fmaf(a5, bf_lo(u5), acc.x); acc.y = fmaf(a5, bf_hi(u5), acc.y);
        acc.x = fmaf(a6, bf_lo(u6), acc.x); acc.y = fmaf(a6, bf_hi(u6), acc.y);
        acc.x = fmaf(a7, bf_lo(u7), acc.x); acc.y = fmaf(a7, bf_hi(u7), acc.y);
    }
    for (; j < je; ++j) {
        long q = __builtin_nontemporal_load(spackl + j);
        int r = __builtin_amdgcn_readfirstlane((int)q);
        unsigned uu = hb[(size_t)r * 64 + lane];
        float a = dis[r] * __uint_as_float((unsigned)((unsigned long)q >> 32));
        acc.x = fmaf(a, bf_lo(uu), acc.x);
        acc.y = fmaf(a, bf_hi(uu), acc.y);
    }

    int c0 = lane * 2;
    float2 bv = *(const float2*)(bias + c0);
    float2 o;
    o.x = bv.x + dn * acc.x;
    o.y = bv.y + dn * acc.y;
    union { float2 f; double d; } cvt;
    cvt.f = o;
    __builtin_nontemporal_store(cvt.d, (double*)(out + (size_t)node * 128 + c0));
}

extern "C" void kernel_launch(void* const* d_in, const int* in_sizes, int n_in,
                              void* d_out, int out_size, void* d_ws, size_t ws_size,
                              hipStream_t stream) {
    const float* x     = (const float*)d_in[0];
    const int*   eidx  = (const int*)d_in[1];   // [2,E] int32
    const float* eattr = (const float*)d_in[2];
    const float* W     = (const float*)d_in[3];
    const float* bias  = (const float*)d_in[4];
    int N = in_sizes[0] / 128;
    int E = in_sizes[2];
    const int* row = eidx;
    const int* col = eidx + E;

    int NC = (N + 127) >> 7;                       // 782 coarse buckets
    int NBLK = (E + CHUNK - 1) / CHUNK;            // 782 hist/place blocks

    char* p = (char*)d_ws;
    auto carve = [&](size_t bytes) {
        char* q = p;
        p += (bytes + 255) & ~(size_t)255;
        return q;
    };
    unsigned short* h   = (unsigned short*)carve((size_t)N * 128 * sizeof(unsigned short));
    unsigned short* Wtg = (unsigned short*)carve(128 * 128 * sizeof(unsigned short));
    float* dis    = (float*)carve((size_t)N * sizeof(float));
    int*   rowptr = (int*)carve((size_t)(N + 1) * sizeof(int));
    int*   histg  = (int*)carve((size_t)NC * NBLK * sizeof(int));
    int2*  srw    = (int2*)carve((size_t)E * sizeof(int2));
    int2*  spack  = (int2*)carve((size_t)E * sizeof(int2));
    int*   bsum   = (int*)carve(256 * sizeof(int));
    int*   boff   = (int*)carve(256 * sizeof(int));

    int M = NC * NBLK;
    int NBs = (M + ELEMS_PER_SCAN_BLOCK - 1) / ELEMS_PER_SCAN_BLOCK;  // 150 <= 256
    int GB  = (N + 63) / 64;   // 1563 gemm blocks
    int GB1 = GB / 2;          // ride pg
    int GB2 = GB - GB1;        // ride fine

    k_hist<<<NBLK, 256, 0, stream>>>(col, W, histg, Wtg, E, NC, NBLK);
    k_scan1<<<NBs, 256, 0, stream>>>(histg, histg, bsum, M);
    k_scan2<<<1, 256, 0, stream>>>(bsum, boff, NBs);
    k_pg<<<NBLK + GB1, 256, 0, stream>>>(row, col, eattr, histg, boff, srw,
                                         x, Wtg, h, E, N, NC, NBLK, 0);
    k_fine<<<NC + GB2, 256, 0, stream>>>(histg, boff, srw, rowptr, dis, spack,
                                         x, Wtg, h, E, N, NC, NBLK, GB1);
    {
        size_t threads = (size_t)N * 64;
        int blocks = (int)((threads + 255) / 256);
        k_gather<<<blocks, 256, 0, stream>>>((const unsigned int*)h, dis, rowptr,
                                             (const long*)spack, bias, (float*)d_out, N);
    }
}

// Round 13
// 248.920 us; speedup vs baseline: 1.0385x; 1.0112x over previous
//
#include <hip/hip_runtime.h>

// GCNConv: out = D^-1/2 (A+I) D^-1/2 X W + b
// N=100000, E=1600000, Din=Dout=128; x/W/b fp32, edge_index int32, out fp32.
//
// R17 = R12 dataflow (248.5us best) + dis folded into h (h' = dis ⊙ h):
//   out = b + dn*(h'[node] + sum_e w_e * h'[r_e])   with dn = dis[node]
//   - gather loses the per-edge random dis[r] broadcast load (1.6M reqs,
//     ~16-20% of its request/line traffic) and one dependent-load stage.
//   - gemm scales its epilogue by dis[grow] (coalesced), so it must run
//     AFTER fine -> standalone dispatch. Rider experiments (R13-R16)
//     proved riders are additive, so position is free; pg/fine drop
//     their rider branches (simpler, same occupancy).
//   Pipeline: hist(+wprep) -> scan1 -> scan2 -> place -> fine -> gemm -> gather.

#define ELEMS_PER_SCAN_BLOCK 4096  // 256 threads * 16
#define SCAN_SHIFT 12
#define CHUNK 2048                 // edges per hist/place block
#define NCMAX 800                  // >= NC = ceil(N/128) = 782

typedef __attribute__((ext_vector_type(8))) short short8;
typedef __attribute__((ext_vector_type(4))) float f32x4;

__device__ inline unsigned short f2bf(float f) {  // fp32 -> bf16 RNE
    unsigned u = __float_as_uint(f);
    u += 0x7fffu + ((u >> 16) & 1u);
    return (unsigned short)(u >> 16);
}
__device__ inline float bf_lo(unsigned u) { return __uint_as_float(u << 16); }
__device__ inline float bf_hi(unsigned u) { return __uint_as_float(u & 0xffff0000u); }

// ---- coarse histogram + W-prep fold (4KB LDS, high occupancy) ----
__global__ __launch_bounds__(256) void k_hist(const int* __restrict__ col,
                                              const float* __restrict__ W,
                                              int* __restrict__ histg,
                                              unsigned short* __restrict__ Wtg,
                                              int E, int NC, int NBLK) {
    __shared__ int lh[1024];
    int t = threadIdx.x, blk = blockIdx.x;
    if (blk < 64) {  // W transpose+bf16: 2 rows per block
        int n = blk * 2 + (t >> 7);
        int k = t & 127;
        Wtg[n * 128 + k] = f2bf(W[k * 128 + n]);
    }
    for (int i = t; i < 1024; i += 256) lh[i] = 0;
    __syncthreads();
    int base = blk * CHUNK;
    #pragma unroll
    for (int i = 0; i < CHUNK / 256; ++i) {
        int e = base + i * 256 + t;
        if (e < E) atomicAdd(&lh[col[e] >> 7], 1);
    }
    __syncthreads();
    for (int b = t; b < NC; b += 256) histg[b * NBLK + blk] = lh[b];
}

__device__ inline int wave_incl_scan(int x, int lane) {
    #pragma unroll
    for (int d = 1; d < 64; d <<= 1) {
        int y = __shfl_up(x, d, 64);
        if (lane >= d) x += y;
    }
    return x;
}

// ---- scans (pure) ----
__global__ void k_scan1(const int* __restrict__ in, int* __restrict__ out,
                        int* __restrict__ bsum, int M) {
    __shared__ int wsum[4];
    __shared__ int woff[4];
    int t = threadIdx.x, lane = t & 63, wid = t >> 6;
    int base = blockIdx.x * ELEMS_PER_SCAN_BLOCK + t * 16;
    int v[16];
    #pragma unroll
    for (int i = 0; i < 16; ++i) v[i] = (base + i < M) ? in[base + i] : 0;
    int run = 0;
    #pragma unroll
    for (int i = 0; i < 16; ++i) { int x = v[i]; v[i] = run; run += x; }
    int incl = wave_incl_scan(run, lane);
    int excl = incl - run;
    if (lane == 63) wsum[wid] = incl;
    __syncthreads();
    if (t == 0) {
        int r = 0;
        #pragma unroll
        for (int w = 0; w < 4; ++w) { int s = wsum[w]; woff[w] = r; r += s; }
        bsum[blockIdx.x] = r;
    }
    __syncthreads();
    int off = woff[wid] + excl;
    #pragma unroll
    for (int i = 0; i < 16; ++i)
        if (base + i < M) out[base + i] = v[i] + off;
}

__global__ void k_scan2(const int* __restrict__ bsum, int* __restrict__ boff, int NB) {
    __shared__ int wsum[4];
    __shared__ int woff[4];
    int t = threadIdx.x, lane = t & 63, wid = t >> 6;
    int x = (t < NB) ? bsum[t] : 0;
    int incl = wave_incl_scan(x, lane);
    int excl = incl - x;
    if (lane == 63) wsum[wid] = incl;
    __syncthreads();
    if (t == 0) {
        int r = 0;
        #pragma unroll
        for (int w = 0; w < 4; ++w) { int s = wsum[w]; woff[w] = r; r += s; }
    }
    __syncthreads();
    if (t < NB) boff[t] = woff[wid] + excl;
}

// ---- place: LDS-staged bucket-sorted coalesced output (pure) ----
__global__ __launch_bounds__(256) void k_place(const int* __restrict__ row,
                                               const int* __restrict__ col,
                                               const float* __restrict__ wgt,
                                               const int* __restrict__ histg,
                                               const int* __restrict__ boff,
                                               int2* __restrict__ srw,
                                               int E, int NC, int NBLK) {
    __shared__ struct { int lcnt[NCMAX]; int gadj[NCMAX]; int2 stage[CHUNK];
                        int sdst[CHUNK]; int wsum[4]; int woff[4]; } sp;  // 30.0 KB
    int t = threadIdx.x, blk = blockIdx.x;
    int lane = t & 63, wid = t >> 6;
    int base = blk * CHUNK;
    int nE = min(CHUNK, E - base);
    for (int b = t; b < NCMAX; b += 256) sp.lcnt[b] = 0;
    __syncthreads();
    // pass A: local count
    #pragma unroll
    for (int i = 0; i < CHUNK / 256; ++i) {
        int e = base + i * 256 + t;
        if (e < E) atomicAdd(&sp.lcnt[col[e] >> 7], 1);
    }
    __syncthreads();
    // block-wide exclusive scan of lcnt[0..NCMAX), 4 entries/thread
    int c4[4];
    int sum = 0;
    #pragma unroll
    for (int i = 0; i < 4; ++i) {
        int idx = t * 4 + i;
        int v = (idx < NCMAX) ? sp.lcnt[idx] : 0;
        c4[i] = sum; sum += v;
    }
    int incl = wave_incl_scan(sum, lane);
    int excl = incl - sum;
    if (lane == 63) sp.wsum[wid] = incl;
    __syncthreads();
    if (t == 0) {
        int r = 0;
        #pragma unroll
        for (int w = 0; w < 4; ++w) { int s = sp.wsum[w]; sp.woff[w] = r; r += s; }
    }
    __syncthreads();
    int tb = sp.woff[wid] + excl;
    __syncthreads();
    #pragma unroll
    for (int i = 0; i < 4; ++i) {
        int idx = t * 4 + i;
        if (idx < NCMAX) {
            int b0 = tb + c4[i];
            int gb = 0;
            if (idx < NC) {
                int g = idx * NBLK + blk;
                gb = histg[g] + boff[g >> SCAN_SHIFT];  // scan3 folded
            }
            sp.gadj[idx] = gb - b0;
            sp.lcnt[idx] = b0;
        }
    }
    __syncthreads();
    // pass B: scatter into LDS by bucket
    #pragma unroll
    for (int i = 0; i < CHUNK / 256; ++i) {
        int e = base + i * 256 + t;
        if (e < E) {
            int c = col[e];
            int slot = atomicAdd(&sp.lcnt[c >> 7], 1);
            sp.stage[slot] = make_int2(((c & 127) << 17) | row[e], __float_as_int(wgt[e]));
            sp.sdst[slot] = sp.gadj[c >> 7] + slot;
        }
    }
    __syncthreads();
    for (int s_ = t; s_ < nE; s_ += 256) {
        srw[sp.sdst[s_]] = sp.stage[s_];
    }
}

// ---- fine: exact CSR within each 128-node bucket + dis + spack (pure) ----
__global__ __launch_bounds__(256) void k_fine(const int* __restrict__ histg,
                                              const int* __restrict__ boff,
                                              const int2* __restrict__ srw,
                                              int* __restrict__ rowptr,
                                              float* __restrict__ dis,
                                              int2* __restrict__ spack,
                                              int E, int N, int NC, int NBLK) {
    __shared__ struct { int2 sbuf[3072]; int cnt128[128]; float degf[128];
                        int cur128[128]; int wtot[2]; } sf;   // 25.7 KB
    int t = threadIdx.x, b = blockIdx.x;
    int nb = b << 7;
    int g0 = b * NBLK;
    int start = histg[g0] + boff[g0 >> SCAN_SHIFT];
    int end;
    if (b == NC - 1) end = E;
    else {
        int g1 = (b + 1) * NBLK;
        end = histg[g1] + boff[g1 >> SCAN_SHIFT];
    }
    int cnt = end - start;
    int NL = min(cnt, 3072);
    if (t < 128) { sf.cnt128[t] = 0; sf.degf[t] = 1.0f; }  // 1.0 = self-loop
    __syncthreads();
    // phase 1: single global read; stage first NL entries into LDS
    for (int j = t; j < cnt; j += 256) {
        int2 s = srw[start + j];
        if (j < NL) sf.sbuf[j] = s;
        int c = s.x >> 17;
        atomicAdd(&sf.cnt128[c], 1);
        atomicAdd(&sf.degf[c], __int_as_float(s.y));
    }
    __syncthreads();
    // phase 2: 128-entry exclusive scan, write rowptr/dis, seed cursors
    int v = 0, incl = 0;
    if (t < 128) {
        v = sf.cnt128[t];
        incl = wave_incl_scan(v, t & 63);
        if ((t & 63) == 63) sf.wtot[t >> 6] = incl;
    }
    __syncthreads();
    if (t < 128) {
        int excl = incl - v + ((t >= 64) ? sf.wtot[0] : 0);
        int p = start + excl;
        sf.cur128[t] = p;
        int n = nb + t;
        if (n < N) {
            rowptr[n] = p;
            dis[n] = rsqrtf(sf.degf[t]);
        }
    }
    if (t == 0 && b == NC - 1) rowptr[N] = E;
    __syncthreads();
    // phase 3: final placement from LDS (global for rare overflow)
    for (int j = t; j < cnt; j += 256) {
        int2 s = (j < NL) ? sf.sbuf[j] : srw[start + j];
        int c = s.x >> 17;
        int pos = atomicAdd(&sf.cur128[c], 1);
        spack[pos] = make_int2(s.x & 0x1FFFF, s.y);
    }
}

// ---- gemm: h' = (x @ W) scaled by dis (runs AFTER fine) ----
__global__ __launch_bounds__(256) void k_gemm(const float* __restrict__ x,
                                              const unsigned short* __restrict__ Wtg,
                                              const float* __restrict__ dis,
                                              unsigned short* __restrict__ h, int N) {
    __shared__ struct { short Xs[64][72]; short Ws[128][72]; } sm;  // 27.6 KB
    int t = threadIdx.x;
    int lane = t & 63, wid = t >> 6;
    int row0 = blockIdx.x * 64;
    int q = lane >> 4;
    int m = lane & 15;
    f32x4 acc[8];
    #pragma unroll
    for (int tde = 0; tde < 8; ++tde) acc[tde] = (f32x4){0.f, 0.f, 0.f, 0.f};

    #pragma unroll
    for (int kh = 0; kh < 2; ++kh) {
        {   // X half: 64 rows x 64 K; 16 floats/thread
            int r = t >> 2;
            int kf = (t & 3) * 16;
            int gr = row0 + r;
            const float4* src = (const float4*)(x + (size_t)gr * 128 + kh * 64 + kf);
            float4 a0 = make_float4(0.f, 0.f, 0.f, 0.f), a1 = a0, a2 = a0, a3 = a0;
            if (gr < N) { a0 = src[0]; a1 = src[1]; a2 = src[2]; a3 = src[3]; }
            short8 p0, p1;
            p0[0] = (short)f2bf(a0.x); p0[1] = (short)f2bf(a0.y);
            p0[2] = (short)f2bf(a0.z); p0[3] = (short)f2bf(a0.w);
            p0[4] = (short)f2bf(a1.x); p0[5] = (short)f2bf(a1.y);
            p0[6] = (short)f2bf(a1.z); p0[7] = (short)f2bf(a1.w);
            p1[0] = (short)f2bf(a2.x); p1[1] = (short)f2bf(a2.y);
            p1[2] = (short)f2bf(a2.z); p1[3] = (short)f2bf(a2.w);
            p1[4] = (short)f2bf(a3.x); p1[5] = (short)f2bf(a3.y);
            p1[6] = (short)f2bf(a3.z); p1[7] = (short)f2bf(a3.w);
            *(short8*)&sm.Xs[r][kf]     = p0;
            *(short8*)&sm.Xs[r][kf + 8] = p1;
        }
        {   // W half: 128 rows x 64 K; 32 shorts/thread
            int n = t >> 1;
            int off = (t & 1) * 32;
            const short* wsrc = (const short*)Wtg + n * 128 + kh * 64 + off;
            #pragma unroll
            for (int i = 0; i < 4; ++i)
                *(short8*)&sm.Ws[n][off + 8 * i] = *(const short8*)(wsrc + 8 * i);
        }
        __syncthreads();
        #pragma unroll
        for (int kc = 0; kc < 64; kc += 32) {
            short8 af = *(const short8*)&sm.Xs[wid * 16 + m][kc + q * 8];
            #pragma unroll
            for (int tde = 0; tde < 8; ++tde) {
                short8 bf = *(const short8*)&sm.Ws[tde * 16 + m][kc + q * 8];
                acc[tde] = __builtin_amdgcn_mfma_f32_16x16x32_bf16(af, bf, acc[tde], 0, 0, 0);
            }
        }
        __syncthreads();
    }
    #pragma unroll
    for (int r = 0; r < 4; ++r) {
        int grow = row0 + wid * 16 + q * 4 + r;
        if (grow < N) {
            float dn = dis[grow];   // coalesced/broadcast; folds D^-1/2 into h
            #pragma unroll
            for (int tde = 0; tde < 8; ++tde)
                h[(size_t)grow * 128 + tde * 16 + m] = f2bf(dn * acc[tde][r]);
        }
    }
}

// ---- gather: R4 loop on h' — NO per-edge dis load ----
__global__ __launch_bounds__(256) void k_gather(const unsigned int* __restrict__ hb,
                                                const float* __restrict__ dis,
                                                const int* __restrict__ rowptr,
                                                const long* __restrict__ spackl,
                                                const float* __restrict__ bias,
                                                float* __restrict__ out, int N) {
    int gid = blockIdx.x * blockDim.x + threadIdx.x;
    int node = gid >> 6;
    int lane = gid & 63;
    if (node >= N) return;
    node = __builtin_amdgcn_readfirstlane(node);

    float dn = dis[node];
    unsigned u = hb[(size_t)node * 64 + lane];   // h'[node] = dn*h[node]
    float2 acc;
    acc.x = bf_lo(u);
    acc.y = bf_hi(u);

    int jb = rowptr[node], je = rowptr[node + 1];
    int j = jb;
    for (; j + 8 <= je; j += 8) {   // 8 h'-rows in flight
        long q0 = __builtin_nontemporal_load(spackl + j);
        long q1 = __builtin_nontemporal_load(spackl + j + 1);
        long q2 = __builtin_nontemporal_load(spackl + j + 2);
        long q3 = __builtin_nontemporal_load(spackl + j + 3);
        long q4 = __builtin_nontemporal_load(spackl + j + 4);
        long q5 = __builtin_nontemporal_load(spackl + j + 5);
        long q6 = __builtin_nontemporal_load(spackl + j + 6);
        long q7 = __builtin_nontemporal_load(spackl + j + 7);
        int r0 = __builtin_amdgcn_readfirstlane((int)q0);
        int r1 = __builtin_amdgcn_readfirstlane((int)q1);
        int r2 = __builtin_amdgcn_readfirstlane((int)q2);
        int r3 = __builtin_amdgcn_readfirstlane((int)q3);
        int r4 = __builtin_amdgcn_readfirstlane((int)q4);
        int r5 = __builtin_amdgcn_readfirstlane((int)q5);
        int r6 = __builtin_amdgcn_readfirstlane((int)q6);
        int r7 = __builtin_amdgcn_readfirstlane((int)q7);
        unsigned u0 = hb[(size_t)r0 * 64 + lane];
        unsigned u1 = hb[(size_t)r1 * 64 + lane];
        unsigned u2 = hb[(size_t)r2 * 64 + lane];
        unsigned u3 = hb[(size_t)r3 * 64 + lane];
        unsigned u4 = hb[(size_t)r4 * 64 + lane];
        unsigned u5 = hb[(size_t)r5 * 64 + lane];
        unsigned u6 = hb[(size_t)r6 * 64 + lane];
        unsigned u7 = hb[(size_t)r7 * 64 + lane];
        float a0 = __uint_as_float((unsigned)((unsigned long)q0 >> 32));
        float a1 = __uint_as_float((unsigned)((unsigned long)q1 >> 32));
        float a2 = __uint_as_float((unsigned)((unsigned long)q2 >> 32));
        float a3 = __uint_as_float((unsigned)((unsigned long)q3 >> 32));
        float a4 = __uint_as_float((unsigned)((unsigned long)q4 >> 32));
        float a5 = __uint_as_float((unsigned)((unsigned long)q5 >> 32));
        float a6 = __uint_as_float((unsigned)((unsigned long)q6 >> 32));
        float a7 = __uint_as_float((unsigned)((unsigned long)q7 >> 32));
        acc.x = fmaf(a0, bf_lo(u0), acc.x); acc.y = fmaf(a0, bf_hi(u0), acc.y);
        acc.x = fmaf(a1, bf_lo(u1), acc.x); acc.y = fmaf(a1, bf_hi(u1), acc.y);
        acc.x = fmaf(a2, bf_lo(u2), acc.x); acc.y = fmaf(a2, bf_hi(u2), acc.y);
        acc.x = fmaf(a3, bf_lo(u3), acc.x); acc.y = fmaf(a3, bf_hi(u3), acc.y);
        acc.x = fmaf(a4, bf_lo(u4), acc.x); acc.y = fmaf(a4, bf_hi(u4), acc.y);
        acc.x = fmaf(a5, bf_lo(u5), acc.x); acc.y = fmaf(a5, bf_hi(u5), acc.y);
        acc.x = fmaf(a6, bf_lo(u6), acc.x); acc.y = fmaf(a6, bf_hi(u6), acc.y);
        acc.x = fmaf(a7, bf_lo(u7), acc.x); acc.y = fmaf(a7, bf_hi(u7), acc.y);
    }
    for (; j < je; ++j) {
        long q = __builtin_nontemporal_load(spackl + j);
        int r = __builtin_amdgcn_readfirstlane((int)q);
        unsigned uu = hb[(size_t)r * 64 + lane];
        float a = __uint_as_float((unsigned)((unsigned long)q >> 32));
        acc.x = fmaf(a, bf_lo(uu), acc.x);
        acc.y = fmaf(a, bf_hi(uu), acc.y);
    }

    int c0 = lane * 2;
    float2 bv = *(const float2*)(bias + c0);
    float2 o;
    o.x = bv.x + dn * acc.x;
    o.y = bv.y + dn * acc.y;
    union { float2 f; double d; } cvt;
    cvt.f = o;
    __builtin_nontemporal_store(cvt.d, (double*)(out + (size_t)node * 128 + c0));
}

extern "C" void kernel_launch(void* const* d_in, const int* in_sizes, int n_in,
                              void* d_out, int out_size, void* d_ws, size_t ws_size,
                              hipStream_t stream) {
    const float* x     = (const float*)d_in[0];
    const int*   eidx  = (const int*)d_in[1];   // [2,E] int32
    const float* eattr = (const float*)d_in[2];
    const float* W     = (const float*)d_in[3];
    const float* bias  = (const float*)d_in[4];
    int N = in_sizes[0] / 128;
    int E = in_sizes[2];
    const int* row = eidx;
    const int* col = eidx + E;

    int NC = (N + 127) >> 7;                       // 782 coarse buckets
    int NBLK = (E + CHUNK - 1) / CHUNK;            // 782 hist/place blocks

    char* p = (char*)d_ws;
    auto carve = [&](size_t bytes) {
        char* q = p;
        p += (bytes + 255) & ~(size_t)255;
        return q;
    };
    unsigned short* h   = (unsigned short*)carve((size_t)N * 128 * sizeof(unsigned short));
    unsigned short* Wtg = (unsigned short*)carve(128 * 128 * sizeof(unsigned short));
    float* dis    = (float*)carve((size_t)N * sizeof(float));
    int*   rowptr = (int*)carve((size_t)(N + 1) * sizeof(int));
    int*   histg  = (int*)carve((size_t)NC * NBLK * sizeof(int));
    int2*  srw    = (int2*)carve((size_t)E * sizeof(int2));
    int2*  spack  = (int2*)carve((size_t)E * sizeof(int2));
    int*   bsum   = (int*)carve(256 * sizeof(int));
    int*   boff   = (int*)carve(256 * sizeof(int));

    int M = NC * NBLK;
    int NBs = (M + ELEMS_PER_SCAN_BLOCK - 1) / ELEMS_PER_SCAN_BLOCK;  // 150 <= 256
    int GB = (N + 63) / 64;   // 1563 gemm blocks

    k_hist<<<NBLK, 256, 0, stream>>>(col, W, histg, Wtg, E, NC, NBLK);
    k_scan1<<<NBs, 256, 0, stream>>>(histg, histg, bsum, M);
    k_scan2<<<1, 256, 0, stream>>>(bsum, boff, NBs);
    k_place<<<NBLK, 256, 0, stream>>>(row, col, eattr, histg, boff, srw, E, NC, NBLK);
    k_fine<<<NC, 256, 0, stream>>>(histg, boff, srw, rowptr, dis, spack, E, N, NC, NBLK);
    k_gemm<<<GB, 256, 0, stream>>>(x, Wtg, dis, h, N);
    {
        size_t threads = (size_t)N * 64;
        int blocks = (int)((threads + 255) / 256);
        k_gather<<<blocks, 256, 0, stream>>>((const unsigned int*)h, dis, rowptr,
                                             (const long*)spack, bias, (float*)d_out, N);
    }
}